// Round 1
// baseline (39711.151 us; speedup 1.0000x reference)
//
#include <hip/hip_runtime.h>

#define N 4096
#define IN_DIM 128
#define T_STEPS 2048
#define KSLOTS 576          // ELL row capacity: mean nnz 409.6, sd 19.2 -> max over 4096 rows ~490
#define NBLOCKS 256
#define NTHREADS 1024
#define WAVES_PER_BLOCK (NTHREADS / 64)

// ---------------------------------------------------------------------------
// Kernel 1: compress dense W (4096x4096, ~10% nnz) into padded ELL.
// vals[r*KSLOTS + s] (f32), cols[...] (u16), chunks[r] = ceil(nnz/64).
// Slots [nnz, chunks*64) are zero-filled so the step kernel loop is guard-free.
// ---------------------------------------------------------------------------
__global__ void build_ell(const float* __restrict__ W,
                          float* __restrict__ vals,
                          unsigned short* __restrict__ cols,
                          int* __restrict__ chunks) {
    __shared__ int cnt;
    const int r = blockIdx.x;
    if (threadIdx.x == 0) cnt = 0;
    __syncthreads();
    const float* wrow = W + (size_t)r * N;
    float* vrow = vals + (size_t)r * KSLOTS;
    unsigned short* crow = cols + (size_t)r * KSLOTS;
    for (int j = threadIdx.x; j < N; j += blockDim.x) {
        float w = wrow[j];
        if (w != 0.0f) {
            int p = atomicAdd(&cnt, 1);
            if (p < KSLOTS) { vrow[p] = w; crow[p] = (unsigned short)j; }
        }
    }
    __syncthreads();
    const int n = cnt;
    const int ch = (n + 63) >> 6;
    const int padded = ch << 6;
    for (int j = n + (int)threadIdx.x; j < padded; j += blockDim.x) {
        vrow[j] = 0.0f;
        crow[j] = 0;
    }
    if (threadIdx.x == 0) chunks[r] = ch;
}

// ---------------------------------------------------------------------------
// Kernel 2: persistent cooperative step kernel.
// 256 blocks x 1024 threads = 4096 waves; wave g owns reservoir row g forever.
//  - W_in row preloaded into 2 regs/lane once (outside t loop)
//  - per step: stage h_{t-1} (from out[t-1]) + x_t into LDS, sparse dot via
//    ELL chunks with LDS gather, wave-reduce, leaky tanh update, write out[t]
//  - grid sync: monotone atomic arrival counter (target = (t+1)*gridDim.x).
//    Monotone counter => no reset race; one-step skew is safe because each
//    step writes a distinct out row (history array = state buffer).
// ---------------------------------------------------------------------------
__global__ void __launch_bounds__(NTHREADS, 1) esn_steps(
    const float* __restrict__ x,
    const float* __restrict__ W_in,
    const float* __restrict__ vals,
    const unsigned short* __restrict__ cols,
    const int* __restrict__ chunks,
    float* __restrict__ out,
    int* __restrict__ barrier_cnt) {

    __shared__ float h_lds[N];       // full previous state, 16 KB
    __shared__ float x_lds[IN_DIM];  // current input row

    const int tid  = threadIdx.x;
    const int lane = tid & 63;
    const int wave = tid >> 6;
    const int r    = blockIdx.x * WAVES_PER_BLOCK + wave;  // 0..4095, fixed row

    // Per-row constants, loaded once.
    const float w0 = W_in[r * IN_DIM + lane];
    const float w1 = W_in[r * IN_DIM + 64 + lane];
    const int   ch = chunks[r];
    const float* __restrict__ vp = vals + (size_t)r * KSLOTS;
    const unsigned short* __restrict__ cp = cols + (size_t)r * KSLOTS;
    const int nb = gridDim.x;

    for (int t = 0; t < T_STEPS; ++t) {
        // ---- stage h_{t-1} and x_t into LDS ----
        float4 hv;
        if (t > 0) {
            hv = ((const float4*)(out + (size_t)(t - 1) * N))[tid];
        } else {
            hv = make_float4(0.f, 0.f, 0.f, 0.f);
        }
        ((float4*)h_lds)[tid] = hv;
        if (tid < IN_DIM) x_lds[tid] = x[t * IN_DIM + tid];
        __syncthreads();

        // ---- row dot: input part + sparse recurrent part ----
        float acc = w0 * x_lds[lane] + w1 * x_lds[64 + lane];
        for (int i = 0; i < ch; ++i) {
            float v = vp[(i << 6) + lane];
            int   c = cp[(i << 6) + lane];
            acc += v * h_lds[c];
        }
        // wave64 reduce
        #pragma unroll
        for (int off = 32; off > 0; off >>= 1) acc += __shfl_down(acc, off);

        if (lane == 0) {
            float hp = h_lds[r];
            float hn = 0.7f * hp + 0.3f * tanhf(acc);
            out[(size_t)t * N + r] = hn;
        }
        __syncthreads();  // all h_lds reads done; all out[t] row writes issued

        // ---- grid barrier ----
        if (tid == 0) {
            __threadfence();  // release out[t] writes at agent scope
            __hip_atomic_fetch_add(barrier_cnt, 1, __ATOMIC_ACQ_REL,
                                   __HIP_MEMORY_SCOPE_AGENT);
            const int target = (t + 1) * nb;
            while (__hip_atomic_load(barrier_cnt, __ATOMIC_ACQUIRE,
                                     __HIP_MEMORY_SCOPE_AGENT) < target) {
                __builtin_amdgcn_s_sleep(1);
            }
            __threadfence();  // acquire: invalidate stale caches before reads
        }
        __syncthreads();
    }
}

// ---------------------------------------------------------------------------
// Workspace layout (bytes):
//   [0, 1024)                         barrier counter (memset 0 per launch)
//   [1024, +N*KSLOTS*4)               ELL vals (f32)      9.44 MB
//   [.., +N*KSLOTS*2)                 ELL cols (u16)      4.72 MB
//   [.., +N*4)                        chunk counts        16 KB
// total ~14.2 MB
// ---------------------------------------------------------------------------
extern "C" void kernel_launch(void* const* d_in, const int* in_sizes, int n_in,
                              void* d_out, int out_size, void* d_ws, size_t ws_size,
                              hipStream_t stream) {
    const float* x    = (const float*)d_in[0];  // [2048,128]
    const float* W_in = (const float*)d_in[1];  // [4096,128]
    const float* W    = (const float*)d_in[2];  // [4096,4096]
    float* out = (float*)d_out;                 // [2048,4096]

    char* ws = (char*)d_ws;
    int* bar = (int*)ws;
    float* vals = (float*)(ws + 1024);
    unsigned short* cols = (unsigned short*)(ws + 1024 + (size_t)N * KSLOTS * 4);
    int* chunks = (int*)(ws + 1024 + (size_t)N * KSLOTS * 6);

    hipMemsetAsync(bar, 0, 1024, stream);
    build_ell<<<N, 256, 0, stream>>>(W, vals, cols, chunks);

    void* args[] = {(void*)&x, (void*)&W_in, (void*)&vals, (void*)&cols,
                    (void*)&chunks, (void*)&out, (void*)&bar};
    hipLaunchCooperativeKernel((void*)esn_steps, dim3(NBLOCKS), dim3(NTHREADS),
                               args, 0, stream);
}

// Round 2
// 14483.813 us; speedup vs baseline: 2.7418x; 2.7418x over previous
//
#include <hip/hip_runtime.h>

#define N 4096
#define IN_DIM 128
#define T_STEPS 2048
#define KSLOTS 576           // uniform padded ELL row width; max nnz ~490 (mean 409.6, sd 19.2)
#define CHUNKS (KSLOTS / 64) // 9, uniform for all rows
#define NBLOCKS 64
#define NTHREADS 1024
#define WAVES_PER_BLOCK (NTHREADS / 64)
#define ROWS_PER_WAVE 4
#define FLAG_STRIDE 32       // ints -> 128 B between flags (own cacheline each)

// ---------------------------------------------------------------------------
// Kernel 1: compress dense W into uniform padded ELL (all rows KSLOTS wide,
// zero-filled) so the step kernel loop is guard-free and uniform.
// ---------------------------------------------------------------------------
__global__ void build_ell(const float* __restrict__ W,
                          float* __restrict__ vals,
                          unsigned short* __restrict__ cols) {
    __shared__ int cnt;
    const int r = blockIdx.x;
    if (threadIdx.x == 0) cnt = 0;
    __syncthreads();
    const float* wrow = W + (size_t)r * N;
    float* vrow = vals + (size_t)r * KSLOTS;
    unsigned short* crow = cols + (size_t)r * KSLOTS;
    for (int j = threadIdx.x; j < N; j += blockDim.x) {
        float w = wrow[j];
        if (w != 0.0f) {
            int p = atomicAdd(&cnt, 1);
            if (p < KSLOTS) { vrow[p] = w; crow[p] = (unsigned short)j; }
        }
    }
    __syncthreads();
    const int n = cnt;
    for (int j = n + (int)threadIdx.x; j < KSLOTS; j += blockDim.x) {
        vrow[j] = 0.0f;   // zero value -> padding contributes nothing
        crow[j] = 0;
    }
}

// ---------------------------------------------------------------------------
// Kernel 2: persistent cooperative step kernel.
// 64 blocks x 1024 threads; each wave owns 4 consecutive reservoir rows.
// Grid barrier: per-block arrival flag (own cacheline, monotone store of t+1),
// all blocks' wave-0 lanes poll all 64 flags in parallel (relaxed agent
// loads), single acquire fence on exit. No RMW contention anywhere.
// One-step skew is safe: each step writes a distinct out row.
// ---------------------------------------------------------------------------
__global__ void __launch_bounds__(NTHREADS, 1) esn_steps(
    const float* __restrict__ x,
    const float* __restrict__ W_in,
    const float* __restrict__ vals,
    const unsigned short* __restrict__ cols,
    float* __restrict__ out,
    int* __restrict__ flags) {

    __shared__ float h_lds[N];       // full previous state, 16 KB
    __shared__ float x_lds[IN_DIM];

    const int tid  = threadIdx.x;
    const int lane = tid & 63;
    const int wave = tid >> 6;
    const int base = (blockIdx.x * WAVES_PER_BLOCK + wave) * ROWS_PER_WAVE; // 4-aligned

    // Per-row constants, loaded once (outside the t loop).
    float w0[ROWS_PER_WAVE], w1[ROWS_PER_WAVE];
    #pragma unroll
    for (int j = 0; j < ROWS_PER_WAVE; ++j) {
        w0[j] = W_in[(base + j) * IN_DIM + lane];
        w1[j] = W_in[(base + j) * IN_DIM + 64 + lane];
    }
    const float* __restrict__ vp = vals + (size_t)base * KSLOTS;
    const unsigned short* __restrict__ cp = cols + (size_t)base * KSLOTS;

    for (int t = 0; t < T_STEPS; ++t) {
        // ---- stage h_{t-1} and x_t into LDS ----
        float4 hv;
        if (t > 0) {
            hv = ((const float4*)(out + (size_t)(t - 1) * N))[tid];
        } else {
            hv = make_float4(0.f, 0.f, 0.f, 0.f);
        }
        ((float4*)h_lds)[tid] = hv;
        if (tid < IN_DIM) x_lds[tid] = x[t * IN_DIM + tid];
        __syncthreads();

        // ---- 4 row dots: input part + sparse recurrent part (uniform 9 chunks) ----
        float acc[ROWS_PER_WAVE];
        #pragma unroll
        for (int j = 0; j < ROWS_PER_WAVE; ++j)
            acc[j] = w0[j] * x_lds[lane] + w1[j] * x_lds[64 + lane];

        for (int i = 0; i < CHUNKS; ++i) {
            #pragma unroll
            for (int j = 0; j < ROWS_PER_WAVE; ++j) {   // 4 independent chains -> ILP
                float v = vp[j * KSLOTS + (i << 6) + lane];
                int   c = cp[j * KSLOTS + (i << 6) + lane];
                acc[j] += v * h_lds[c];
            }
        }

        // butterfly reduce each acc[j] across the wave
        #pragma unroll
        for (int j = 0; j < ROWS_PER_WAVE; ++j) {
            #pragma unroll
            for (int off = 32; off > 0; off >>= 1)
                acc[j] += __shfl_xor(acc[j], off);
        }

        if (lane == 0) {
            float4 hp = *((const float4*)&h_lds[base]);
            float4 hn;
            hn.x = 0.7f * hp.x + 0.3f * tanhf(acc[0]);
            hn.y = 0.7f * hp.y + 0.3f * tanhf(acc[1]);
            hn.z = 0.7f * hp.z + 0.3f * tanhf(acc[2]);
            hn.w = 0.7f * hp.w + 0.3f * tanhf(acc[3]);
            *((float4*)(out + (size_t)t * N + base)) = hn;
        }
        __syncthreads();  // all h_lds reads done; all waves' out[t] stores drained (vmcnt)

        // ---- grid barrier: flag store + all-poll ----
        if (tid == 0) {
            __threadfence();  // release: writeback L2 so out[t] is visible cross-XCD
            __hip_atomic_store(&flags[blockIdx.x * FLAG_STRIDE], t + 1,
                               __ATOMIC_RELEASE, __HIP_MEMORY_SCOPE_AGENT);
        }
        if (tid < NBLOCKS) {
            while (__hip_atomic_load(&flags[tid * FLAG_STRIDE], __ATOMIC_RELAXED,
                                     __HIP_MEMORY_SCOPE_AGENT) < t + 1) {
                __builtin_amdgcn_s_sleep(1);
            }
            // wave reconverges when every lane's flag has arrived
            if (tid == 0) __threadfence();  // acquire: invalidate stale lines
        }
        __syncthreads();
    }
}

// ---------------------------------------------------------------------------
// Workspace layout (bytes):
//   [0, 8192)                 arrival flags (64 x 128 B, memset 0 per launch)
//   [8192, +N*KSLOTS*4)       ELL vals (f32)   9.44 MB
//   [.., +N*KSLOTS*2)         ELL cols (u16)   4.72 MB
// ---------------------------------------------------------------------------
extern "C" void kernel_launch(void* const* d_in, const int* in_sizes, int n_in,
                              void* d_out, int out_size, void* d_ws, size_t ws_size,
                              hipStream_t stream) {
    const float* x    = (const float*)d_in[0];  // [2048,128]
    const float* W_in = (const float*)d_in[1];  // [4096,128]
    const float* W    = (const float*)d_in[2];  // [4096,4096]
    float* out = (float*)d_out;                 // [2048,4096]

    char* ws = (char*)d_ws;
    int* flags = (int*)ws;
    float* vals = (float*)(ws + 8192);
    unsigned short* cols = (unsigned short*)(ws + 8192 + (size_t)N * KSLOTS * 4);

    hipMemsetAsync(flags, 0, 8192, stream);
    build_ell<<<N, 256, 0, stream>>>(W, vals, cols);

    void* args[] = {(void*)&x, (void*)&W_in, (void*)&vals, (void*)&cols,
                    (void*)&out, (void*)&flags};
    hipLaunchCooperativeKernel((void*)esn_steps, dim3(NBLOCKS), dim3(NTHREADS),
                               args, 0, stream);
}

// Round 3
// 11377.975 us; speedup vs baseline: 3.4902x; 1.2730x over previous
//
#include <hip/hip_runtime.h>

#define N 4096
#define IN_DIM 128
#define T_STEPS 2048
#define KSLOTS 576           // uniform padded ELL row width; max nnz ~490 (mean 409.6, sd 19.2)
#define CHUNKS (KSLOTS / 64) // 9, uniform for all rows
#define NBLOCKS 256
#define NTHREADS 1024
#define WAVES_PER_BLOCK (NTHREADS / 64)

// ---------------------------------------------------------------------------
// Kernel 1: compress dense W into uniform padded ELL with BANK-AWARE chunk
// assignment: each row's nnz are distributed so that, within each 64-wide
// chunk, every LDS bank (col % 32) is hit ~2x (2-way is free on gfx950).
// Bank b's k-th entry goes to chunk (k+b)%CHUNKS, linear-probing on overflow.
// Padding slots are val=0, col=0 (same-address -> LDS broadcast, free).
// Any assignment is numerically correct; this only shapes conflicts.
// ---------------------------------------------------------------------------
__global__ void build_ell(const float* __restrict__ W,
                          float* __restrict__ vals,
                          unsigned short* __restrict__ cols) {
    __shared__ float sval[KSLOTS];
    __shared__ unsigned short scol[KSLOTS];
    __shared__ float slot_val[KSLOTS];
    __shared__ unsigned short slot_col[KSLOTS];
    __shared__ int chunk_fill[CHUNKS];
    __shared__ int cnt;

    const int r = blockIdx.x;
    const int tid = threadIdx.x;
    if (tid == 0) cnt = 0;
    if (tid < CHUNKS) chunk_fill[tid] = 0;
    __syncthreads();

    // phase 1: compact nnz of row r into LDS
    const float* wrow = W + (size_t)r * N;
    for (int j = tid; j < N; j += blockDim.x) {
        float w = wrow[j];
        if (w != 0.0f) {
            int p = atomicAdd(&cnt, 1);
            if (p < KSLOTS) { sval[p] = w; scol[p] = (unsigned short)j; }
        }
    }
    __syncthreads();
    // init all slots to padding
    for (int j = tid; j < KSLOTS; j += blockDim.x) { slot_val[j] = 0.0f; slot_col[j] = 0; }
    __syncthreads();

    // phase 2: 32 threads (one per bank) assign entries to chunks
    if (tid < 32) {
        int k = 0;
        const int n = (cnt < KSLOTS) ? cnt : KSLOTS;
        for (int p = 0; p < n; ++p) {
            int c = scol[p];
            if ((c & 31) == tid) {
                int ch0 = (k + tid) % CHUNKS;
                for (int probe = 0; probe < CHUNKS; ++probe) {
                    int cc = ch0 + probe; if (cc >= CHUNKS) cc -= CHUNKS;
                    int pos = atomicAdd(&chunk_fill[cc], 1);
                    if (pos < 64) {
                        slot_val[cc * 64 + pos] = sval[p];
                        slot_col[cc * 64 + pos] = (unsigned short)c;
                        break;
                    }
                }
                ++k;
            }
        }
    }
    __syncthreads();

    // phase 3: write slots to global ELL
    float* vrow = vals + (size_t)r * KSLOTS;
    unsigned short* crow = cols + (size_t)r * KSLOTS;
    for (int j = tid; j < KSLOTS; j += blockDim.x) { vrow[j] = slot_val[j]; crow[j] = slot_col[j]; }
}

// ---------------------------------------------------------------------------
// Kernel 2: persistent cooperative step kernel. 256 blocks x 1024 threads
// = 4096 waves; wave g owns reservoir row g forever (1 row/wave -> LDS and
// L2 load spread over all 256 CUs).
//
// Fence-free barrier: h values are written with agent-scope RELAXED atomic
// stores (write-through to the LLC coherence point, no dirty L2).
// __syncthreads drains every wave's vmcnt, so all h stores are globally
// visible before tid0's relaxed flag store. Readers poll packed flags with
// relaxed atomic loads (bypass L1); their h loads are per-step-fresh
// addresses -> cold miss -> fresh data from LLC. No __threadfence anywhere.
// One-step skew is safe: each step writes a distinct out row.
// ---------------------------------------------------------------------------
__global__ void __launch_bounds__(NTHREADS, 1) esn_steps(
    const float* __restrict__ x,
    const float* __restrict__ W_in,
    const float* __restrict__ vals,
    const unsigned short* __restrict__ cols,
    float* __restrict__ out,
    int* __restrict__ flags) {

    __shared__ float h_lds[N];       // full previous state, 16 KB
    __shared__ float x_lds[IN_DIM];

    const int tid  = threadIdx.x;
    const int lane = tid & 63;
    const int wave = tid >> 6;
    const int r    = blockIdx.x * WAVES_PER_BLOCK + wave;  // 0..4095, fixed row

    // Per-row constants, loaded once.
    const float w0 = W_in[r * IN_DIM + lane];
    const float w1 = W_in[r * IN_DIM + 64 + lane];
    const float* __restrict__ vp = vals + (size_t)r * KSLOTS;
    const unsigned short* __restrict__ cp = cols + (size_t)r * KSLOTS;

    for (int t = 0; t < T_STEPS; ++t) {
        // ---- stage h_{t-1} and x_t into LDS ----
        float4 hv;
        if (t > 0) {
            hv = ((const float4*)(out + (size_t)(t - 1) * N))[tid];
        } else {
            hv = make_float4(0.f, 0.f, 0.f, 0.f);
        }
        ((float4*)h_lds)[tid] = hv;
        if (tid < IN_DIM) x_lds[tid] = x[t * IN_DIM + tid];
        __syncthreads();

        // ---- row dot: input part + sparse recurrent part (9 uniform chunks) ----
        float acc = w0 * x_lds[lane] + w1 * x_lds[64 + lane];
        #pragma unroll
        for (int i = 0; i < CHUNKS; ++i) {
            float v = vp[(i << 6) + lane];
            int   c = cp[(i << 6) + lane];
            acc += v * h_lds[c];
        }
        // butterfly reduce across the wave
        #pragma unroll
        for (int off = 32; off > 0; off >>= 1) acc += __shfl_xor(acc, off);

        if (lane == 0) {
            float hp = h_lds[r];
            float hn = 0.7f * hp + 0.3f * tanhf(acc);
            // write-through store: globally visible at LLC when vmcnt acks
            __hip_atomic_store(&out[(size_t)t * N + r], hn,
                               __ATOMIC_RELAXED, __HIP_MEMORY_SCOPE_AGENT);
        }
        // drains every wave's outstanding stores (s_waitcnt vmcnt(0) before
        // s_barrier) AND covers all h_lds reads for next-iteration overwrite
        __syncthreads();

        // ---- grid barrier: relaxed flag store + coalesced all-poll ----
        if (tid == 0) {
            __hip_atomic_store(&flags[blockIdx.x], t + 1,
                               __ATOMIC_RELAXED, __HIP_MEMORY_SCOPE_AGENT);
        }
        if (wave == 0) {
            const int tgt = t + 1;
            for (;;) {
                int f0 = __hip_atomic_load(&flags[lane], __ATOMIC_RELAXED,
                                           __HIP_MEMORY_SCOPE_AGENT);
                int f1 = __hip_atomic_load(&flags[lane + 64], __ATOMIC_RELAXED,
                                           __HIP_MEMORY_SCOPE_AGENT);
                int f2 = __hip_atomic_load(&flags[lane + 128], __ATOMIC_RELAXED,
                                           __HIP_MEMORY_SCOPE_AGENT);
                int f3 = __hip_atomic_load(&flags[lane + 192], __ATOMIC_RELAXED,
                                           __HIP_MEMORY_SCOPE_AGENT);
                int m01 = (f0 < f1) ? f0 : f1;
                int m23 = (f2 < f3) ? f2 : f3;
                if (((m01 < m23) ? m01 : m23) >= tgt) break;
                __builtin_amdgcn_s_sleep(1);
            }
        }
        __syncthreads();
    }
}

// ---------------------------------------------------------------------------
// Workspace layout (bytes):
//   [0, 1024)                 arrival flags (256 x int, packed; memset 0)
//   [1024, +N*KSLOTS*4)       ELL vals (f32)   9.44 MB
//   [.., +N*KSLOTS*2)         ELL cols (u16)   4.72 MB
// ---------------------------------------------------------------------------
extern "C" void kernel_launch(void* const* d_in, const int* in_sizes, int n_in,
                              void* d_out, int out_size, void* d_ws, size_t ws_size,
                              hipStream_t stream) {
    const float* x    = (const float*)d_in[0];  // [2048,128]
    const float* W_in = (const float*)d_in[1];  // [4096,128]
    const float* W    = (const float*)d_in[2];  // [4096,4096]
    float* out = (float*)d_out;                 // [2048,4096]

    char* ws = (char*)d_ws;
    int* flags = (int*)ws;
    float* vals = (float*)(ws + 1024);
    unsigned short* cols = (unsigned short*)(ws + 1024 + (size_t)N * KSLOTS * 4);

    hipMemsetAsync(flags, 0, 1024, stream);
    build_ell<<<N, 256, 0, stream>>>(W, vals, cols);

    void* args[] = {(void*)&x, (void*)&W_in, (void*)&vals, (void*)&cols,
                    (void*)&out, (void*)&flags};
    hipLaunchCooperativeKernel((void*)esn_steps, dim3(NBLOCKS), dim3(NTHREADS),
                               args, 0, stream);
}

// Round 4
// 10859.061 us; speedup vs baseline: 3.6570x; 1.0478x over previous
//
#include <hip/hip_runtime.h>

#define N 4096
#define IN_DIM 128
#define T_STEPS 2048
#define KSLOTS 576           // uniform padded ELL row width; max nnz ~490 (mean 409.6, sd 19.2)
#define CHUNKS (KSLOTS / 64) // 9, uniform for all rows
#define NBLOCKS 256
#define NTHREADS 1024
#define WAVES_PER_BLOCK (NTHREADS / 64)
#define SENTINEL_BITS 0x7FC00001u   // quiet NaN; h is never NaN -> unambiguous "not yet written"

// ---------------------------------------------------------------------------
// Kernel 0: fill the entire out buffer with the NaN sentinel, WRITE-THROUGH
// (agent-scope atomic stores) so the sentinel is visible at the LLC coherence
// point before any step-kernel poll (which bypasses caches). This defends
// against the harness's 0xAA poison AND stale valid floats from a previous
// timed replay, both of which are non-NaN and would look "ready".
// ---------------------------------------------------------------------------
__global__ void init_sentinel(float* __restrict__ out) {
    const size_t i = (size_t)blockIdx.x * blockDim.x + threadIdx.x;
    __hip_atomic_store(&out[i], __uint_as_float(SENTINEL_BITS),
                       __ATOMIC_RELAXED, __HIP_MEMORY_SCOPE_AGENT);
}

// ---------------------------------------------------------------------------
// Kernel 1: compress dense W into uniform padded ELL with BANK-AWARE chunk
// assignment: within each 64-wide chunk every LDS bank (col % 32) is hit ~2x
// (2-way is free on gfx950). Padding slots are val=0, col=0 (broadcast, free).
// ---------------------------------------------------------------------------
__global__ void build_ell(const float* __restrict__ W,
                          float* __restrict__ vals,
                          unsigned short* __restrict__ cols) {
    __shared__ float sval[KSLOTS];
    __shared__ unsigned short scol[KSLOTS];
    __shared__ float slot_val[KSLOTS];
    __shared__ unsigned short slot_col[KSLOTS];
    __shared__ int chunk_fill[CHUNKS];
    __shared__ int cnt;

    const int r = blockIdx.x;
    const int tid = threadIdx.x;
    if (tid == 0) cnt = 0;
    if (tid < CHUNKS) chunk_fill[tid] = 0;
    __syncthreads();

    const float* wrow = W + (size_t)r * N;
    for (int j = tid; j < N; j += blockDim.x) {
        float w = wrow[j];
        if (w != 0.0f) {
            int p = atomicAdd(&cnt, 1);
            if (p < KSLOTS) { sval[p] = w; scol[p] = (unsigned short)j; }
        }
    }
    __syncthreads();
    for (int j = tid; j < KSLOTS; j += blockDim.x) { slot_val[j] = 0.0f; slot_col[j] = 0; }
    __syncthreads();

    if (tid < 32) {  // one thread per bank distributes its entries across chunks
        int k = 0;
        const int n = (cnt < KSLOTS) ? cnt : KSLOTS;
        for (int p = 0; p < n; ++p) {
            int c = scol[p];
            if ((c & 31) == tid) {
                int ch0 = (k + tid) % CHUNKS;
                for (int probe = 0; probe < CHUNKS; ++probe) {
                    int cc = ch0 + probe; if (cc >= CHUNKS) cc -= CHUNKS;
                    int pos = atomicAdd(&chunk_fill[cc], 1);
                    if (pos < 64) {
                        slot_val[cc * 64 + pos] = sval[p];
                        slot_col[cc * 64 + pos] = (unsigned short)c;
                        break;
                    }
                }
                ++k;
            }
        }
    }
    __syncthreads();

    float* vrow = vals + (size_t)r * KSLOTS;
    unsigned short* crow = cols + (size_t)r * KSLOTS;
    for (int j = tid; j < KSLOTS; j += blockDim.x) { vrow[j] = slot_val[j]; crow[j] = slot_col[j]; }
}

// ---------------------------------------------------------------------------
// Kernel 2: persistent step kernel, NO grid barrier, NO flags.
// Dataflow sync: producers write h rows of out[t] with write-through relaxed
// agent stores; consumers poll out[t-1] with cache-bypassing relaxed agent
// loads until non-NaN. One LLC hop producer->consumer. Skew is self-limiting
// (a block can't start step t until every block finished step t-1); each
// block writes only its own 16 rows -> no write hazards at any skew.
// ---------------------------------------------------------------------------
__global__ void __launch_bounds__(NTHREADS, 1) esn_steps(
    const float* __restrict__ x,
    const float* __restrict__ W_in,
    const float* __restrict__ vals,
    const unsigned short* __restrict__ cols,
    float* __restrict__ out) {

    __shared__ float h_lds[N];       // full previous state, 16 KB
    __shared__ float x_lds[IN_DIM];

    const int tid  = threadIdx.x;
    const int lane = tid & 63;
    const int wave = tid >> 6;
    const int r    = blockIdx.x * WAVES_PER_BLOCK + wave;  // fixed row

    const float w0 = W_in[r * IN_DIM + lane];
    const float w1 = W_in[r * IN_DIM + 64 + lane];
    const float* __restrict__ vp = vals + (size_t)r * KSLOTS;
    const unsigned short* __restrict__ cp = cols + (size_t)r * KSLOTS;

    for (int t = 0; t < T_STEPS; ++t) {
        // ---- stage x_t (overlaps with h poll below) ----
        if (tid < IN_DIM) x_lds[tid] = x[t * IN_DIM + tid];

        // ---- stage h_{t-1}: poll data directly until non-sentinel ----
        const int i4 = tid << 2;
        float v0, v1, v2, v3;
        if (t > 0) {
            const float* hrow = out + (size_t)(t - 1) * N;
            v0 = __hip_atomic_load(&hrow[i4 + 0], __ATOMIC_RELAXED, __HIP_MEMORY_SCOPE_AGENT);
            v1 = __hip_atomic_load(&hrow[i4 + 1], __ATOMIC_RELAXED, __HIP_MEMORY_SCOPE_AGENT);
            v2 = __hip_atomic_load(&hrow[i4 + 2], __ATOMIC_RELAXED, __HIP_MEMORY_SCOPE_AGENT);
            v3 = __hip_atomic_load(&hrow[i4 + 3], __ATOMIC_RELAXED, __HIP_MEMORY_SCOPE_AGENT);
            while (v0 != v0 || v1 != v1 || v2 != v2 || v3 != v3) {
                __builtin_amdgcn_s_sleep(2);
                v0 = __hip_atomic_load(&hrow[i4 + 0], __ATOMIC_RELAXED, __HIP_MEMORY_SCOPE_AGENT);
                v1 = __hip_atomic_load(&hrow[i4 + 1], __ATOMIC_RELAXED, __HIP_MEMORY_SCOPE_AGENT);
                v2 = __hip_atomic_load(&hrow[i4 + 2], __ATOMIC_RELAXED, __HIP_MEMORY_SCOPE_AGENT);
                v3 = __hip_atomic_load(&hrow[i4 + 3], __ATOMIC_RELAXED, __HIP_MEMORY_SCOPE_AGENT);
            }
        } else {
            v0 = v1 = v2 = v3 = 0.0f;
        }
        h_lds[i4 + 0] = v0;
        h_lds[i4 + 1] = v1;
        h_lds[i4 + 2] = v2;
        h_lds[i4 + 3] = v3;
        __syncthreads();

        // ---- row dot: input part + sparse recurrent part (9 uniform chunks) ----
        float acc = w0 * x_lds[lane] + w1 * x_lds[64 + lane];
        #pragma unroll
        for (int i = 0; i < CHUNKS; ++i) {
            float v = vp[(i << 6) + lane];
            int   c = cp[(i << 6) + lane];
            acc += v * h_lds[c];
        }
        #pragma unroll
        for (int off = 32; off > 0; off >>= 1) acc += __shfl_xor(acc, off);

        if (lane == 0) {
            float hp = h_lds[r];
            float hn = 0.7f * hp + 0.3f * tanhf(acc);
            // write-through: visible at LLC to pollers, no fence needed
            __hip_atomic_store(&out[(size_t)t * N + r], hn,
                               __ATOMIC_RELAXED, __HIP_MEMORY_SCOPE_AGENT);
        }
        __syncthreads();   // protect h_lds/x_lds before next-step overwrite
    }
}

// ---------------------------------------------------------------------------
// Workspace layout (bytes):
//   [0, +N*KSLOTS*4)       ELL vals (f32)   9.44 MB
//   [.., +N*KSLOTS*2)      ELL cols (u16)   4.72 MB
// ---------------------------------------------------------------------------
extern "C" void kernel_launch(void* const* d_in, const int* in_sizes, int n_in,
                              void* d_out, int out_size, void* d_ws, size_t ws_size,
                              hipStream_t stream) {
    const float* x    = (const float*)d_in[0];  // [2048,128]
    const float* W_in = (const float*)d_in[1];  // [4096,128]
    const float* W    = (const float*)d_in[2];  // [4096,4096]
    float* out = (float*)d_out;                 // [2048,4096]

    char* ws = (char*)d_ws;
    float* vals = (float*)ws;
    unsigned short* cols = (unsigned short*)(ws + (size_t)N * KSLOTS * 4);

    // T*N = 8,388,608 floats = 8192 blocks x 1024 threads
    init_sentinel<<<(T_STEPS * N) / NTHREADS, NTHREADS, 0, stream>>>(out);
    build_ell<<<N, 256, 0, stream>>>(W, vals, cols);

    void* args[] = {(void*)&x, (void*)&W_in, (void*)&vals, (void*)&cols, (void*)&out};
    hipLaunchCooperativeKernel((void*)esn_steps, dim3(NBLOCKS), dim3(NTHREADS),
                               args, 0, stream);
}

// Round 5
// 7771.053 us; speedup vs baseline: 5.1101x; 1.3974x over previous
//
#include <hip/hip_runtime.h>

#define N 4096
#define IN_DIM 128
#define T_STEPS 2048
#define KSLOTS 576           // uniform padded ELL row width; max nnz ~490 (mean 409.6, sd 19.2)
#define CHUNKS (KSLOTS / 64) // 9, uniform for all rows
#define NBLOCKS 256
#define NTHREADS 1024
#define WAVES_PER_BLOCK (NTHREADS / 64)
#define SENTINEL_BITS 0x7FC00001u   // qNaN; h is always finite -> producers never write this pattern

typedef float f32x4 __attribute__((ext_vector_type(4)));

// ---------------------------------------------------------------------------
// Kernel 0: fill out with the sentinel, write-through (agent scope) so it is
// at the coherence point before any step-kernel poll. Defends against 0xAA
// poison and stale floats from a previous replay (both non-sentinel).
// ---------------------------------------------------------------------------
__global__ void init_sentinel(float* __restrict__ out) {
    const size_t i = (size_t)blockIdx.x * blockDim.x + threadIdx.x;
    __hip_atomic_store(&out[i], __uint_as_float(SENTINEL_BITS),
                       __ATOMIC_RELAXED, __HIP_MEMORY_SCOPE_AGENT);
}

// ---------------------------------------------------------------------------
// Kernel 1: dense W -> uniform padded ELL with bank-aware chunk assignment
// (each 64-slot chunk hits every LDS bank ~2x; 2-way is free on gfx950).
// Padding: val=0, col=0 (same-address broadcast, free).
// ---------------------------------------------------------------------------
__global__ void build_ell(const float* __restrict__ W,
                          float* __restrict__ vals,
                          unsigned short* __restrict__ cols) {
    __shared__ float sval[KSLOTS];
    __shared__ unsigned short scol[KSLOTS];
    __shared__ float slot_val[KSLOTS];
    __shared__ unsigned short slot_col[KSLOTS];
    __shared__ int chunk_fill[CHUNKS];
    __shared__ int cnt;

    const int r = blockIdx.x;
    const int tid = threadIdx.x;
    if (tid == 0) cnt = 0;
    if (tid < CHUNKS) chunk_fill[tid] = 0;
    __syncthreads();

    const float* wrow = W + (size_t)r * N;
    for (int j = tid; j < N; j += blockDim.x) {
        float w = wrow[j];
        if (w != 0.0f) {
            int p = atomicAdd(&cnt, 1);
            if (p < KSLOTS) { sval[p] = w; scol[p] = (unsigned short)j; }
        }
    }
    __syncthreads();
    for (int j = tid; j < KSLOTS; j += blockDim.x) { slot_val[j] = 0.0f; slot_col[j] = 0; }
    __syncthreads();

    if (tid < 32) {  // one thread per bank spreads its entries across chunks
        int k = 0;
        const int n = (cnt < KSLOTS) ? cnt : KSLOTS;
        for (int p = 0; p < n; ++p) {
            int c = scol[p];
            if ((c & 31) == tid) {
                int ch0 = (k + tid) % CHUNKS;
                for (int probe = 0; probe < CHUNKS; ++probe) {
                    int cc = ch0 + probe; if (cc >= CHUNKS) cc -= CHUNKS;
                    int pos = atomicAdd(&chunk_fill[cc], 1);
                    if (pos < 64) {
                        slot_val[cc * 64 + pos] = sval[p];
                        slot_col[cc * 64 + pos] = (unsigned short)c;
                        break;
                    }
                }
                ++k;
            }
        }
    }
    __syncthreads();

    float* vrow = vals + (size_t)r * KSLOTS;
    unsigned short* crow = cols + (size_t)r * KSLOTS;
    for (int j = tid; j < KSLOTS; j += blockDim.x) { vrow[j] = slot_val[j]; crow[j] = slot_col[j]; }
}

// ---------------------------------------------------------------------------
// Coherent 16B load straight from the coherence point (bypasses L1+L2).
// The s_waitcnt lives inside the asm because the compiler does not track
// vmcnt for asm-issued loads.
// ---------------------------------------------------------------------------
__device__ __forceinline__ f32x4 load_coherent_x4(const float* p) {
    f32x4 v;
    asm volatile("global_load_dwordx4 %0, %1, off sc0 sc1\n\t"
                 "s_waitcnt vmcnt(0)"
                 : "=v"(v) : "v"(p) : "memory");
    return v;
}

// ---------------------------------------------------------------------------
// Kernel 2: persistent step kernel, barrier-free (data-as-flag).
//  - ELL vals/cols hoisted into VGPRs before the t-loop (step-invariant):
//    the step loop does zero L2 traffic for weights.
//  - consumers poll out[t-1] with coalesced coherent dwordx4 loads until the
//    sentinel is gone; producers write h rows write-through. One LLC hop.
//  - skew self-limits at 1 step; each block writes only its own rows.
// ---------------------------------------------------------------------------
__global__ void __launch_bounds__(NTHREADS, 1) esn_steps(
    const float* __restrict__ x,
    const float* __restrict__ W_in,
    const float* __restrict__ vals,
    const unsigned short* __restrict__ cols,
    float* __restrict__ out) {

    __shared__ float h_lds[N];       // full previous state, 16 KB
    __shared__ float x_lds[IN_DIM];

    const int tid  = threadIdx.x;
    const int lane = tid & 63;
    const int wave = tid >> 6;
    const int r    = blockIdx.x * WAVES_PER_BLOCK + wave;  // fixed row

    const float w0 = W_in[r * IN_DIM + lane];
    const float w1 = W_in[r * IN_DIM + 64 + lane];

    // Hoist this lane's entire ELL slice into registers (9 vals + 9 offsets).
    const float* __restrict__ vp = vals + (size_t)r * KSLOTS;
    const unsigned short* __restrict__ cp = cols + (size_t)r * KSLOTS;
    float rv[CHUNKS];
    int   rc[CHUNKS];   // byte offsets into h_lds
    #pragma unroll
    for (int i = 0; i < CHUNKS; ++i) {
        rv[i] = vp[(i << 6) + lane];
        rc[i] = ((int)cp[(i << 6) + lane]) << 2;
    }

    const int i4 = tid << 2;

    for (int t = 0; t < T_STEPS; ++t) {
        // ---- stage x_t ----
        if (tid < IN_DIM) x_lds[tid] = x[t * IN_DIM + tid];

        // ---- stage h_{t-1}: coalesced coherent poll until sentinel gone ----
        f32x4 hv;
        if (t > 0) {
            const float* addr = out + (size_t)(t - 1) * N + i4;
            for (;;) {
                hv = load_coherent_x4(addr);
                bool not_ready = (__float_as_uint(hv.x) == SENTINEL_BITS) |
                                 (__float_as_uint(hv.y) == SENTINEL_BITS) |
                                 (__float_as_uint(hv.z) == SENTINEL_BITS) |
                                 (__float_as_uint(hv.w) == SENTINEL_BITS);
                if (!not_ready) break;
                __builtin_amdgcn_s_sleep(1);
            }
        } else {
            hv = (f32x4)(0.0f);
        }
        ((f32x4*)h_lds)[tid] = hv;
        __syncthreads();

        // ---- row dot: input part + register-ELL sparse part ----
        float acc = w0 * x_lds[lane] + w1 * x_lds[64 + lane];
        #pragma unroll
        for (int i = 0; i < CHUNKS; ++i) {
            acc += rv[i] * *(const float*)((const char*)h_lds + rc[i]);
        }
        #pragma unroll
        for (int off = 32; off > 0; off >>= 1) acc += __shfl_xor(acc, off);

        if (lane == 0) {
            float hp = h_lds[r];
            float hn = 0.7f * hp + 0.3f * tanhf(acc);
            // write-through: visible at the coherence point, no fence needed
            __hip_atomic_store(&out[(size_t)t * N + r], hn,
                               __ATOMIC_RELAXED, __HIP_MEMORY_SCOPE_AGENT);
        }
        __syncthreads();   // protect h_lds/x_lds before next-step overwrite
    }
}

// ---------------------------------------------------------------------------
// Workspace layout (bytes):
//   [0, +N*KSLOTS*4)       ELL vals (f32)   9.44 MB
//   [.., +N*KSLOTS*2)      ELL cols (u16)   4.72 MB
// ---------------------------------------------------------------------------
extern "C" void kernel_launch(void* const* d_in, const int* in_sizes, int n_in,
                              void* d_out, int out_size, void* d_ws, size_t ws_size,
                              hipStream_t stream) {
    const float* x    = (const float*)d_in[0];  // [2048,128]
    const float* W_in = (const float*)d_in[1];  // [4096,128]
    const float* W    = (const float*)d_in[2];  // [4096,4096]
    float* out = (float*)d_out;                 // [2048,4096]

    char* ws = (char*)d_ws;
    float* vals = (float*)ws;
    unsigned short* cols = (unsigned short*)(ws + (size_t)N * KSLOTS * 4);

    init_sentinel<<<(T_STEPS * N) / NTHREADS, NTHREADS, 0, stream>>>(out);
    build_ell<<<N, 256, 0, stream>>>(W, vals, cols);

    void* args[] = {(void*)&x, (void*)&W_in, (void*)&vals, (void*)&cols, (void*)&out};
    hipLaunchCooperativeKernel((void*)esn_steps, dim3(NBLOCKS), dim3(NTHREADS),
                               args, 0, stream);
}